// Round 4
// baseline (192.520 us; speedup 1.0000x reference)
//
#include <hip/hip_runtime.h>

// DropBlock — v5: two-kernel split (mask once, then pure stream).
//
// v1-v4 post-mortem: four structurally distinct fused schedules (grid 2048/
// 2009/6272 blocks, pipeline depth 2/4/8, nt/plain, loads-all-before-stores)
// ALL converge to 58-65 us (~3.3 TB/s app), while the harness fill kernel
// sustains 6.6 TB/s pure-write at 9% occupancy on the same chip+run. Depth,
// ordering, and vmcnt-queue theories are all refuted by A/B evidence.
// Surviving theory: the per-block mask prologue (12 u-load rounds, 13
// ballots, LDS round-trips, wave-0 serial dilation, 2-3 __syncthreads)
// bubbles the memory pipe between tiny 32 KB streaming bursts — the HBM
// controllers never see a sustained request stream.
//
// v5: kernel A (1 block) computes the 784-entry vfloat4 multiplier table
// into d_ws once. Kernel B is a pure copy-with-multiply: 1 L2-hit table
// load + 4 x loads + 4 nt stores per thread. No barrier, no LDS, no ballot.
// Same-stream launch order provides the A->B dependency (graph-safe).

#define HW      3136   // 56*56
#define WDIM    56
#define HDIM    56
#define HW4     784    // float4s per (n,c) plane
#define ROWMASK 0x00FFFFFFFFFFFFFFull  // low 56 bits
#define NB      6272u                  // stream blocks
#define NT      1605632u               // NB*256 = 784*2048: NT % 784 == 0
#define NVEC    6422528u               // 32*256*784 = 4*NT exactly

typedef float vfloat4 __attribute__((ext_vector_type(4)));

// ---------------------------------------------------------------- kernel A
__global__ void __launch_bounds__(256) dropblock_mask_kernel(
        const float* __restrict__ u, vfloat4* __restrict__ m4) {
    __shared__ unsigned long long chunks[49];    // 3136 seed bits
    __shared__ unsigned long long dropbits[HDIM];
    __shared__ float s_scale;

    // gamma exactly as Python float64 arithmetic, then cast to f32
    const float gamma = (float)(0.1 / 49.0 * (3136.0 / 2500.0));

    const int lane = threadIdx.x & 63;
    const int wave = threadIdx.x >> 6;

    // Phase 1: seed bits via ballot — wave w, chunk 4k+w covers elements
    // [256k + 64w, 256k + 64w + 64).
    #pragma unroll
    for (int k = 0; k < 12; ++k) {
        unsigned long long b = __ballot(u[k * 256 + threadIdx.x] < gamma);
        if (lane == 0) chunks[4 * k + wave] = b;
    }
    if (wave == 0) {  // elements 3072..3135
        unsigned long long b = __ballot(u[3072 + lane] < gamma);
        if (lane == 0) chunks[48] = b;
    }
    __syncthreads();

    // Phase 2: one wave. Lane r: extract row r (56 bits), W-dilate (<<0..6),
    // H-dilate via shfl_up over rows r-6..r, butterfly-reduce kept count.
    if (wave == 0) {
        const int r = lane;
        unsigned long long rd = 0ull;
        if (r < HDIM) {
            int bit = r * WDIM;
            int a = bit >> 6, off = bit & 63;   // off in {0,8,...,56}
            unsigned long long row = chunks[a] >> off;
            if (off > 8) row |= chunks[a + 1] << (64 - off); // a+1 <= 48
            row &= ROWMASK;
            rd = row;
            #pragma unroll
            for (int k = 1; k < 7; ++k) rd |= row << k;
            rd &= ROWMASK;
        }
        unsigned long long d = rd;
        #pragma unroll
        for (int k = 1; k <= 6; ++k)
            d |= __shfl_up(rd, k);              // lanes<k keep own: idempotent
        int kept = 0;
        if (r < HDIM) {
            dropbits[r] = d;
            kept = WDIM - __popcll(d);
        }
        #pragma unroll
        for (int s = 32; s; s >>= 1) kept += __shfl_xor(kept, s);
        if (lane == 0) s_scale = (float)HW / (float)kept;  // exact small-int
    }
    __syncthreads();

    // Phase 3: write the 784-entry vfloat4 multiplier table (12.25 KB).
    {
        const float scale = s_scale;
        for (int q = threadIdx.x; q < HW4; q += 256) {
            const int r = q / 14;               // 14 float4 per 56-wide row
            const int c0 = (q - r * 14) * 4;
            const unsigned long long d = dropbits[r];
            vfloat4 m;
            m[0] = ((d >> c0) & 1ull) ? 0.0f : scale;
            m[1] = ((d >> (c0 + 1)) & 1ull) ? 0.0f : scale;
            m[2] = ((d >> (c0 + 2)) & 1ull) ? 0.0f : scale;
            m[3] = ((d >> (c0 + 3)) & 1ull) ? 0.0f : scale;
            m4[q] = m;
        }
    }
}

// ---------------------------------------------------------------- kernel B
// Pure copy-with-multiply. No barrier, no LDS, no cross-lane op.
// t % 784 is this thread's fixed plane position for ALL 4 elements
// (NT % 784 == 0), so one 16 B table load (L2-hit) covers everything.
__global__ void __launch_bounds__(256) dropblock_stream_kernel(
        const vfloat4* __restrict__ x, vfloat4* __restrict__ out,
        const vfloat4* __restrict__ m4) {
    const unsigned int t = blockIdx.x * 256u + threadIdx.x;
    const vfloat4 m = m4[t % (unsigned int)HW4];
    const vfloat4 a0 = x[t];
    const vfloat4 a1 = x[t + NT];
    const vfloat4 a2 = x[t + 2u * NT];
    const vfloat4 a3 = x[t + 3u * NT];
    __builtin_nontemporal_store(a0 * m, &out[t]);
    __builtin_nontemporal_store(a1 * m, &out[t + NT]);
    __builtin_nontemporal_store(a2 * m, &out[t + 2u * NT]);
    __builtin_nontemporal_store(a3 * m, &out[t + 3u * NT]);
}

extern "C" void kernel_launch(void* const* d_in, const int* in_sizes, int n_in,
                              void* d_out, int out_size, void* d_ws, size_t ws_size,
                              hipStream_t stream) {
    const float* x = (const float*)d_in[0];   // (32,256,56,56) fp32
    const float* u = (const float*)d_in[1];   // (56,56) fp32
    float* out = (float*)d_out;
    vfloat4* m4 = (vfloat4*)d_ws;             // 12.25 KB multiplier table

    dropblock_mask_kernel<<<1, 256, 0, stream>>>(u, m4);
    dropblock_stream_kernel<<<NB, 256, 0, stream>>>(
        (const vfloat4*)x, (vfloat4*)out, m4);
}

// Round 5
// 191.011 us; speedup vs baseline: 1.0079x; 1.0079x over previous
//
#include <hip/hip_runtime.h>

// DropBlock — v6: two-kernel split; stream kernel rebuilt as an m13-clone.
//
// Falsified so far (all ~58-65 us, ~3.4 TB/s app, vs fill's 6.7 TB/s write):
//   v1/v2 nt-hints, v3 pipeline depth, v4 load/store queue order, v5 prologue.
// v5 (prologue-free) was one-shot 4 elems/thread: 25k waves x 8 KB, wave
// lifetime back-computes to ~12.5 us of queuing — memory queues drain at
// every wave turnover. The 6.29 TB/s copy microbench (m13) is the OPPOSITE
// shape: resident grid, many elements/thread, straight-line pipelined body.
// v6 tests the one untested matrix cell: resident grid + prologue-free +
// straight-line multi-element body.
//
//   kernel A (1 block): mask -> 784-entry vfloat4 table in d_ws (12.25 KB).
//   kernel B (2009 blocks): m = one L2-hot table load (t%784 loop-invariant
//     since STRIDE%784==0); then 12 fully-unrolled compile-time-offset
//     load/mul/store pairs + 1 tail. Plain loads (keep L3 read hits),
//     nt stores (write-once stream). 128 VGPR budget to pipeline into.

#define HW      3136   // 56*56
#define WDIM    56
#define HDIM    56
#define HW4     784    // float4s per (n,c) plane
#define ROWMASK 0x00FFFFFFFFFFFFFFull  // low 56 bits
#define NBLOCKS 2009u                  // 49*41: STRIDE % 784 == 0
#define STRIDE  514304u                // NBLOCKS*256 = 784*656
#define NVEC    6422528u               // 32*256*784 = 12*STRIDE + REM
#define REM     250880u                // threads t < REM own a 13th element

typedef float vfloat4 __attribute__((ext_vector_type(4)));

// ---------------------------------------------------------------- kernel A
__global__ void __launch_bounds__(256) dropblock_mask_kernel(
        const float* __restrict__ u, vfloat4* __restrict__ m4) {
    __shared__ unsigned long long chunks[49];    // 3136 seed bits
    __shared__ unsigned long long dropbits[HDIM];
    __shared__ float s_scale;

    // gamma exactly as Python float64 arithmetic, then cast to f32
    const float gamma = (float)(0.1 / 49.0 * (3136.0 / 2500.0));

    const int lane = threadIdx.x & 63;
    const int wave = threadIdx.x >> 6;

    // Phase 1: seed bits via ballot — wave w, chunk 4k+w covers elements
    // [256k + 64w, 256k + 64w + 64).
    #pragma unroll
    for (int k = 0; k < 12; ++k) {
        unsigned long long b = __ballot(u[k * 256 + threadIdx.x] < gamma);
        if (lane == 0) chunks[4 * k + wave] = b;
    }
    if (wave == 0) {  // elements 3072..3135
        unsigned long long b = __ballot(u[3072 + lane] < gamma);
        if (lane == 0) chunks[48] = b;
    }
    __syncthreads();

    // Phase 2: one wave. Lane r: extract row r (56 bits), W-dilate (<<0..6),
    // H-dilate via shfl_up over rows r-6..r, butterfly-reduce kept count.
    if (wave == 0) {
        const int r = lane;
        unsigned long long rd = 0ull;
        if (r < HDIM) {
            int bit = r * WDIM;
            int a = bit >> 6, off = bit & 63;   // off in {0,8,...,56}
            unsigned long long row = chunks[a] >> off;
            if (off > 8) row |= chunks[a + 1] << (64 - off); // a+1 <= 48
            row &= ROWMASK;
            rd = row;
            #pragma unroll
            for (int k = 1; k < 7; ++k) rd |= row << k;
            rd &= ROWMASK;
        }
        unsigned long long d = rd;
        #pragma unroll
        for (int k = 1; k <= 6; ++k)
            d |= __shfl_up(rd, k);              // lanes<k keep own: idempotent
        int kept = 0;
        if (r < HDIM) {
            dropbits[r] = d;
            kept = WDIM - __popcll(d);
        }
        #pragma unroll
        for (int s = 32; s; s >>= 1) kept += __shfl_xor(kept, s);
        if (lane == 0) s_scale = (float)HW / (float)kept;  // exact small-int
    }
    __syncthreads();

    // Phase 3: write the 784-entry vfloat4 multiplier table (12.25 KB).
    {
        const float scale = s_scale;
        for (int q = threadIdx.x; q < HW4; q += 256) {
            const int r = q / 14;               // 14 float4 per 56-wide row
            const int c0 = (q - r * 14) * 4;
            const unsigned long long d = dropbits[r];
            vfloat4 m;
            m[0] = ((d >> c0) & 1ull) ? 0.0f : scale;
            m[1] = ((d >> (c0 + 1)) & 1ull) ? 0.0f : scale;
            m[2] = ((d >> (c0 + 2)) & 1ull) ? 0.0f : scale;
            m[3] = ((d >> (c0 + 3)) & 1ull) ? 0.0f : scale;
            m4[q] = m;
        }
    }
}

// ---------------------------------------------------------------- kernel B
// m13-clone stream: resident grid, straight-line 12-deep body, no barrier,
// no LDS, no cross-lane op. t % 784 is loop-invariant (STRIDE % 784 == 0),
// so ONE table load (L2-hot) covers all 13 elements.
__global__ void __launch_bounds__(256, 4) dropblock_stream_kernel(
        const vfloat4* __restrict__ x, vfloat4* __restrict__ out,
        const vfloat4* __restrict__ m4) {
    const unsigned int t = blockIdx.x * 256u + threadIdx.x;
    const vfloat4 m = m4[t % (unsigned int)HW4];

    // 12 guaranteed elements: t + 11*STRIDE <= 514303 + 5657344 < NVEC.
    // Compile-time offsets; compiler is free to pipeline all 12 loads.
    #pragma unroll
    for (unsigned int k = 0; k < 12; ++k) {
        vfloat4 v = x[t + k * STRIDE];
        __builtin_nontemporal_store(v * m, &out[t + k * STRIDE]);
    }
    // 13th element for the first REM threads.
    if (t < REM) {
        vfloat4 v = x[t + 12u * STRIDE];
        __builtin_nontemporal_store(v * m, &out[t + 12u * STRIDE]);
    }
}

extern "C" void kernel_launch(void* const* d_in, const int* in_sizes, int n_in,
                              void* d_out, int out_size, void* d_ws, size_t ws_size,
                              hipStream_t stream) {
    const float* x = (const float*)d_in[0];   // (32,256,56,56) fp32
    const float* u = (const float*)d_in[1];   // (56,56) fp32
    float* out = (float*)d_out;
    vfloat4* m4 = (vfloat4*)d_ws;             // 12.25 KB multiplier table

    dropblock_mask_kernel<<<1, 256, 0, stream>>>(u, m4);
    dropblock_stream_kernel<<<NBLOCKS, 256, 0, stream>>>(
        (const vfloat4*)x, (vfloat4*)out, m4);
}

// Round 6
// 181.567 us; speedup vs baseline: 1.0603x; 1.0520x over previous
//
#include <hip/hip_runtime.h>

// DropBlock — v7: v4's fused one-shot structure + system-scope no-allocate
// stores (inline asm `global_store_dwordx4 ... nt sc0 sc1`).
//
// Schedule axis is EXHAUSTED: v1-v6 (grid-stride / unrolled / loads-first /
// one-shot / split / resident m13-clone) all land 58-65 us, ~2.5 TB/s
// TCC-side. Surviving theory: harness poison-fill (401 MB) leaves L3 full of
// dirty lines; our read misses force hidden L3->DRAM writebacks and our
// write-ALLOCATIONS (builtin nt only sets the LRU hint, never sc0/sc1)
// contend with the read stream in TCC/L3 -> DRAM side is actually saturated
// (~390 MB in 62 us ~ 6.3 TB/s) which is why no schedule mattered.
// v7 single-variable change vs v4: stores bypass/no-allocate L2+L3
// (nt sc0 sc1). If null, cache-policy axis is falsified too -> roofline.

#define HW      3136   // 56*56
#define WDIM    56
#define HDIM    56
#define HW4     784    // HW/4 float4s per (n,c) plane
#define ROWMASK 0x00FFFFFFFFFFFFFFull  // low 56 bits
#define NB      6272u                  // blocks
#define NT      1605632u               // NB*256 = 12544*128; NT % 784 == 0
#define NVEC    6422528u               // 32*256*784 = 4*NT exactly

typedef float vfloat4 __attribute__((ext_vector_type(4)));

__device__ __forceinline__ void store_nt_bypass(const vfloat4 v, vfloat4* p) {
    // System-scope, non-temporal, no-allocate store: goes to HBM without
    // allocating in TCC(L2)/L3. gfx950 FLAT/GLOBAL accepts sc0 sc1 nt.
    asm volatile("global_store_dwordx4 %0, %1, off nt sc0 sc1"
                 :: "v"(p), "v"(v) : "memory");
}

__global__ void __launch_bounds__(256, 8) dropblock_fused_kernel(
        const float* __restrict__ u, const vfloat4* __restrict__ x,
        vfloat4* __restrict__ out) {
    __shared__ unsigned long long chunks[49];    // 3136 seed bits
    __shared__ unsigned long long dropbits[HDIM];
    __shared__ float s_scale;

    // gamma exactly as Python float64 arithmetic, then cast to f32
    const float gamma = (float)(0.1 / 49.0 * (3136.0 / 2500.0));

    const unsigned int t = blockIdx.x * 256u + threadIdx.x;
    const int lane = threadIdx.x & 63;
    const int wave = threadIdx.x >> 6;

    // --- u loads first (oldest in the vmcnt queue: ballot waits drain only
    // these, not the x loads issued after) ---
    float u0  = u[threadIdx.x];
    float u1  = u[threadIdx.x + 256];
    float u2  = u[threadIdx.x + 512];
    float u3  = u[threadIdx.x + 768];
    float u4  = u[threadIdx.x + 1024];
    float u5  = u[threadIdx.x + 1280];
    float u6  = u[threadIdx.x + 1536];
    float u7  = u[threadIdx.x + 1792];
    float u8  = u[threadIdx.x + 2048];
    float u9  = u[threadIdx.x + 2304];
    float u10 = u[threadIdx.x + 2560];
    float u11 = u[threadIdx.x + 2816];
    float ulast = 0.0f;
    if (wave == 0) ulast = u[3072 + lane];       // elements 3072..3135

    // --- ALL x loads for this thread, issued before any store exists.
    // They complete under the prologue; the __syncthreads drain is free. ---
    vfloat4 a0 = x[t];
    vfloat4 a1 = x[t + NT];
    vfloat4 a2 = x[t + 2u * NT];
    vfloat4 a3 = x[t + 3u * NT];
    __builtin_amdgcn_sched_barrier(0);

    // Phase 1: seed bits via ballot — wave w, chunk 4k+w covers elements
    // [256k + 64w, 256k + 64w + 64).
    {
        unsigned long long b;
        b = __ballot(u0  < gamma); if (lane == 0) chunks[ 0 + wave] = b;
        b = __ballot(u1  < gamma); if (lane == 0) chunks[ 4 + wave] = b;
        b = __ballot(u2  < gamma); if (lane == 0) chunks[ 8 + wave] = b;
        b = __ballot(u3  < gamma); if (lane == 0) chunks[12 + wave] = b;
        b = __ballot(u4  < gamma); if (lane == 0) chunks[16 + wave] = b;
        b = __ballot(u5  < gamma); if (lane == 0) chunks[20 + wave] = b;
        b = __ballot(u6  < gamma); if (lane == 0) chunks[24 + wave] = b;
        b = __ballot(u7  < gamma); if (lane == 0) chunks[28 + wave] = b;
        b = __ballot(u8  < gamma); if (lane == 0) chunks[32 + wave] = b;
        b = __ballot(u9  < gamma); if (lane == 0) chunks[36 + wave] = b;
        b = __ballot(u10 < gamma); if (lane == 0) chunks[40 + wave] = b;
        b = __ballot(u11 < gamma); if (lane == 0) chunks[44 + wave] = b;
        if (wave == 0) {
            b = __ballot(ulast < gamma);
            if (lane == 0) chunks[48] = b;
        }
    }
    __syncthreads();

    // Phase 2: one wave. Lane r: extract row r (56 bits), W-dilate (<<0..6),
    // H-dilate via shfl_up over rows r-6..r, butterfly-reduce kept count.
    if (wave == 0) {
        const int r = lane;
        unsigned long long rd = 0ull;
        if (r < HDIM) {
            int bit = r * WDIM;
            int a = bit >> 6, off = bit & 63;   // off in {0,8,...,56}
            unsigned long long row = chunks[a] >> off;
            if (off > 8) row |= chunks[a + 1] << (64 - off); // a+1 <= 48
            row &= ROWMASK;
            rd = row;
            #pragma unroll
            for (int k = 1; k < 7; ++k) rd |= row << k;
            rd &= ROWMASK;
        }
        unsigned long long d = rd;
        #pragma unroll
        for (int k = 1; k <= 6; ++k)
            d |= __shfl_up(rd, k);              // lanes<k keep own: idempotent
        int kept = 0;
        if (r < HDIM) {
            dropbits[r] = d;
            kept = WDIM - __popcll(d);
        }
        #pragma unroll
        for (int s = 32; s; s >>= 1) kept += __shfl_xor(kept, s);
        if (lane == 0) s_scale = (float)HW / (float)kept;  // exact small-int
    }
    __syncthreads();

    // Phase 3: loop-invariant register multiplier (q = t % 784 fixed since
    // NT % 784 == 0).
    vfloat4 m;
    {
        const unsigned int q = t % (unsigned int)HW4;
        const int r = (int)q / 14;              // 14 float4 per 56-wide row
        const int c0 = ((int)q - r * 14) * 4;
        const unsigned long long d = dropbits[r];
        const float scale = s_scale;
        m[0] = ((d >> c0) & 1ull) ? 0.0f : scale;
        m[1] = ((d >> (c0 + 1)) & 1ull) ? 0.0f : scale;
        m[2] = ((d >> (c0 + 2)) & 1ull) ? 0.0f : scale;
        m[3] = ((d >> (c0 + 3)) & 1ull) ? 0.0f : scale;
    }

    // Phase 4: stores only — system-scope no-allocate non-temporal.
    store_nt_bypass(a0 * m, &out[t]);
    store_nt_bypass(a1 * m, &out[t + NT]);
    store_nt_bypass(a2 * m, &out[t + 2u * NT]);
    store_nt_bypass(a3 * m, &out[t + 3u * NT]);
}

extern "C" void kernel_launch(void* const* d_in, const int* in_sizes, int n_in,
                              void* d_out, int out_size, void* d_ws, size_t ws_size,
                              hipStream_t stream) {
    const float* x = (const float*)d_in[0];   // (32,256,56,56) fp32
    const float* u = (const float*)d_in[1];   // (56,56) fp32
    float* out = (float*)d_out;

    // out_size/16 == NVEC (6,422,528 float4s) == 4*NT — compile-time layout.
    dropblock_fused_kernel<<<NB, 256, 0, stream>>>(
        u, (const vfloat4*)x, (vfloat4*)out);
}